// Round 3
// 132.622 us; speedup vs baseline: 1.0342x; 1.0342x over previous
//
#include <hip/hip_runtime.h>
#include <math.h>

namespace {

constexpr int NQ = 10;
constexpr int NL = 4;
constexpr float PI_F = 3.14159265358979323846f;

// One batch element per wave. Each complex amp packed as f16 {re=lo, im=hi}
// in ONE 32-bit VGPR (carrier type: float). Complex math via v_pk_fma_f16.
// R24 (finer bisect): R0-verbatim EXCEPT layer_gates (layers 1..3) fetch the
// fused row from a per-lane pre-built table via readlane (H1). init_product
// and measurement are byte-for-byte R0. If this fails, the readlane-of-built
// plumbing is the bug; if it passes, R22/R23's init_product hoist (H2) was.

typedef float v2 __attribute__((ext_vector_type(2)));

// ---- GF(2) verification of the absorbed CNOT map (compile-time only) ----
struct M10 { unsigned r[10]; };
constexpr M10 I10{{1u,2u,4u,8u,16u,32u,64u,128u,256u,512u}};
constexpr M10 Fm{{0x003u,0x006u,0x00Cu,0x018u,0x030u,0x060u,0x0C0u,0x180u,0x301u,0x201u}};
constexpr M10 Fi{{0x3FFu,0x3FEu,0x3FCu,0x3F8u,0x3F0u,0x3E0u,0x3C0u,0x380u,0x300u,0x1FFu}};
constexpr M10 mmul(const M10& A, const M10& B) {
  M10 C{};
  for (int p = 0; p < 10; ++p) {
    unsigned v = 0;
    for (int q = 0; q < 10; ++q)
      if ((A.r[p] >> q) & 1u) v ^= B.r[q];
    C.r[p] = v;
  }
  return C;
}
constexpr bool meq(const M10& A, const M10& B) {
  for (int p = 0; p < 10; ++p) if (A.r[p] != B.r[p]) return false;
  return true;
}
static_assert(meq(mmul(Fm, Fi), I10), "Fi is not F^-1");

__device__ __forceinline__ float readlane_f(float v, int lane_const) {
  return __int_as_float(__builtin_amdgcn_readlane(__float_as_int(v), lane_const));
}
__device__ __forceinline__ float bperm_f(int addr4, float v) {
  return __int_as_float(__builtin_amdgcn_ds_bpermute(addr4, __float_as_int(v)));
}
__device__ __forceinline__ float fxor(float v, int m) {
  return __int_as_float(__float_as_int(v) ^ m);
}

// own + partner — direction-agnostic permlane sum (R11-verified); used in
// the measurement butterfly only.
__device__ __forceinline__ float plsum32(float v) {
  float a = v, b = v;
  asm("v_permlane32_swap_b32 %0, %1" : "+v"(a), "+v"(b));
  return a + b;
}
__device__ __forceinline__ float plsum16(float v) {
  float a = v, b = v;
  asm("v_permlane16_swap_b32 %0, %1" : "+v"(a), "+v"(b));
  return a + b;
}

// xor-lane exchange for masks 1,2,8 (DPP) and 4,16,32 (ds_swizzle).
template<int MASK>
__device__ __forceinline__ float lxor(float v) {
  if constexpr (MASK == 1 || MASK == 2 || MASK == 8) {
    constexpr int ctrl = (MASK == 1) ? 0xB1 : (MASK == 2) ? 0x4E : 0x128;
    int i = __float_as_int(v);
    return __int_as_float(__builtin_amdgcn_update_dpp(i, i, ctrl, 0xF, 0xF, true));
  } else {
    return __shfl_xor(v, MASK, 64);
  }
}

// ---- packed complex f16 arithmetic ({re,im} in ONE VGPR) ----
// d = u (*) a
__device__ __forceinline__ float hcmul(float u, float a) {
  float d;
  asm("v_pk_mul_f16 %0, %1, %2 op_sel:[0,0] op_sel_hi:[0,1]\n\t"
      "v_pk_fma_f16 %0, %1, %2, %0 op_sel:[1,1,0] op_sel_hi:[1,0,1] neg_lo:[1,0,0]"
      : "=&v"(d) : "v"(u), "v"(a));
  return d;
}
// d = acc + u (*) a
__device__ __forceinline__ float hcfma(float u, float a, float acc) {
  float d;
  asm("v_pk_fma_f16 %0, %1, %2, %3 op_sel:[0,0,0] op_sel_hi:[0,1,1]\n\t"
      "v_pk_fma_f16 %0, %1, %2, %0 op_sel:[1,1,0] op_sel_hi:[1,0,1] neg_lo:[1,0,0]"
      : "=&v"(d) : "v"(u), "v"(a), "v"(acc));
  return d;
}
// d = conj(u) (*) a
__device__ __forceinline__ float hcmulc(float u, float a) {
  float d;
  asm("v_pk_mul_f16 %0, %1, %2 op_sel:[0,0] op_sel_hi:[0,1]\n\t"
      "v_pk_fma_f16 %0, %1, %2, %0 op_sel:[1,1,0] op_sel_hi:[1,0,1] neg_hi:[1,0,0]"
      : "=&v"(d) : "v"(u), "v"(a));
  return d;
}
// d = acc - conj(u) (*) a
__device__ __forceinline__ float hcfmamc(float u, float a, float acc) {
  float d;
  asm("v_pk_fma_f16 %0, %1, %2, %3 op_sel:[0,0,0] op_sel_hi:[0,1,1] neg_lo:[1,0,0] neg_hi:[1,0,0]\n\t"
      "v_pk_fma_f16 %0, %1, %2, %0 op_sel:[1,1,0] op_sel_hi:[1,0,1] neg_lo:[1,0,0]"
      : "=&v"(d) : "v"(u), "v"(a), "v"(acc));
  return d;
}
// RNE pack: two f32 -> packed f16 pair.
__device__ __forceinline__ float pack16(float x, float y) {
  float lo, hi, d;
  asm("v_cvt_f16_f32 %0, %1" : "=v"(lo) : "v"(x));
  asm("v_cvt_f16_f32 %0, %1" : "=v"(hi) : "v"(y));
  asm("v_pack_b32_f16 %0, %1, %2" : "=v"(d) : "v"(lo), "v"(hi));
  return d;
}
// re^2 + im^2 accumulated in f32.
__device__ __forceinline__ float hdot2(float s, float acc) {
  float d;
  asm("v_dot2_f32_f16 %0, %1, %1, %2" : "=v"(d) : "v"(s), "v"(acc));
  return d;
}

// Gate on state bit P; u00p,u01p = packed f16 first row. sgnh/sgnl: per-lane
// sign masks (bit31 / bit15) for this gate's lane bit (0 for P<4).
// SW: pending xor-32 lane swap on odd regs consumed here (P==9 only).
template<int P, bool SW>
__device__ __forceinline__ void apply_u(float (&s)[16], float u00p, float u01p,
                                        int sgnh, int sgnl) {
  if constexpr (P < 4) {
    constexpr int bit = 1 << P;
#pragma unroll
    for (int r = 0; r < 16; ++r) {
      if ((r & bit) == 0) {
        int r1 = r | bit;
        float a0 = s[r], a1 = s[r1];
        s[r]  = hcfma(u01p, a1, hcmul(u00p, a0));     // u00*a0 + u01*a1
        s[r1] = hcfmamc(u01p, a0, hcmulc(u00p, a1));  // conj(u00)*a1 - conj(u01)*a0
      }
    }
  } else {
    constexpr int mask = 1 << (P - 4);
    // hi lane: self = conj(u00) (flip im=hi sign), partner = -conj(u01)
    // (flip re=lo sign); lo lane: u00, u01.
    float cA = fxor(u00p, sgnh);
    float cB = fxor(u01p, sgnl);
#pragma unroll
    for (int r = 0; r < 16; ++r) {
      float p = lxor<mask>(s[r]);
      if constexpr (SW) {
        if (r & 1) { s[r] = hcfma(cA, p, hcmul(cB, s[r])); continue; }
      }
      s[r] = hcfma(cB, p, hcmul(cA, s[r]));
    }
  }
}

// CNOT chain: (9,8)(8,7)(7,6)(6,5)(5,4) composed bpermute | (4,3) cndmask |
// (3,2)(2,1)(1,0) reg swaps | (0,9) DEFERRED.
__device__ __forceinline__ void cnot_block(float (&s)[16], int lane, int srcl4) {
#pragma unroll
  for (int r = 0; r < 16; ++r)
    s[r] = bperm_f(srcl4, s[r]);
  bool ctrl = (lane & 1) != 0;
#pragma unroll
  for (int r = 0; r < 8; ++r) {
    int r1 = r | 8;
    float t0 = s[r], t1 = s[r1];
    s[r]  = ctrl ? t1 : t0;
    s[r1] = ctrl ? t0 : t1;
  }
#pragma unroll
  for (int r = 8; r < 12; ++r) { float t = s[r]; s[r] = s[r | 4]; s[r | 4] = t; }
  {
    const int rs[4] = {4, 5, 12, 13};
#pragma unroll
    for (int k = 0; k < 4; ++k) {
      int r = rs[k];
      float t = s[r]; s[r] = s[r | 2]; s[r | 2] = t;
    }
  }
#pragma unroll
  for (int r = 2; r < 16; r += 4) { float t = s[r]; s[r] = s[r | 1]; s[r | 1] = t; }
}

// Layer 0 on |0>: product state. Wire w (0..5) -> lane bit (5-w);
// wires 6..9 -> reg bits 3..0. amp = prod of column-0 entries
// (col0 = {u00, -conj(u01)}), built f32 then packed f16.  (R0 VERBATIM.)
__device__ __forceinline__ void init_product(float (&s)[16], const float4* wmat,
                                             float cx, float sx, int lane) {
  float u0p, u1p;
#define C0(i) { float4 wa = wmat[(i)]; \
    v2 wa0 = {wa.x, wa.y}, wa1 = {wa.z, wa.w}; \
    float ca = readlane_f(cx, (i)), sa = readlane_f(sx, (i)); \
    v2 u0 = ca * wa0 + sa * wa1; \
    v2 t01 = ca * wa1 - sa * wa0; \
    u0p = pack16(u0.x, u0.y); \
    u1p = pack16(-t01.x, t01.y); }
  float f;
  C0(0); f = (lane & 32) ? u1p : u0p;
  C0(1); f = hcmul((lane & 16) ? u1p : u0p, f);
  C0(2); f = hcmul((lane & 8) ? u1p : u0p, f);
  C0(3); f = hcmul((lane & 4) ? u1p : u0p, f);
  C0(4); f = hcmul((lane & 2) ? u1p : u0p, f);
  C0(5); f = hcmul((lane & 1) ? u1p : u0p, f);
  float q6_0, q6_1, q7_0, q7_1, q8_0, q8_1, q9_0, q9_1;
  C0(6); q6_0 = u0p; q6_1 = u1p;
  C0(7); q7_0 = u0p; q7_1 = u1p;
  C0(8); q8_0 = u0p; q8_1 = u1p;
  C0(9); q9_0 = u0p; q9_1 = u1p;
#undef C0
  float qa0 = hcmul(q8_0, q9_0), qa1 = hcmul(q8_0, q9_1);
  float qa2 = hcmul(q8_1, q9_0), qa3 = hcmul(q8_1, q9_1);
  float qb0 = hcmul(q6_0, q7_0), qb1 = hcmul(q6_0, q7_1);
  float qb2 = hcmul(q6_1, q7_0), qb3 = hcmul(q6_1, q7_1);
  float fa0 = hcmul(qa0, f), fa1 = hcmul(qa1, f), fa2 = hcmul(qa2, f), fa3 = hcmul(qa3, f);
  s[0]  = hcmul(qb0, fa0); s[1]  = hcmul(qb0, fa1); s[2]  = hcmul(qb0, fa2); s[3]  = hcmul(qb0, fa3);
  s[4]  = hcmul(qb1, fa0); s[5]  = hcmul(qb1, fa1); s[6]  = hcmul(qb1, fa2); s[7]  = hcmul(qb1, fa3);
  s[8]  = hcmul(qb2, fa0); s[9]  = hcmul(qb2, fa1); s[10] = hcmul(qb2, fa2); s[11] = hcmul(qb2, fa3);
  s[12] = hcmul(qb3, fa0); s[13] = hcmul(qb3, fa1); s[14] = hcmul(qb3, fa2); s[15] = hcmul(qb3, fa3);
}

template<bool PEND>
__device__ __forceinline__ void layer_gates(float (&s)[16], float u00L, float u01L,
                                            const int (&sgnh)[6], const int (&sgnl)[6]) {
#define FUSED(i, SW) { \
    float u00p = readlane_f(u00L, (i)); \
    float u01p = readlane_f(u01L, (i)); \
    apply_u<9 - (i), SW>(s, u00p, u01p, \
        ((i) < 6) ? sgnh[5 - (i)] : 0, ((i) < 6) ? sgnl[5 - (i)] : 0); }
  FUSED(0, PEND)            // wire0 = bit9 = lane xor 32; consumes pending swap
  FUSED(1, false) FUSED(2, false) FUSED(3, false) FUSED(4, false)
  FUSED(5, false) FUSED(6, false) FUSED(7, false) FUSED(8, false) FUSED(9, false)
#undef FUSED
}

__global__ __launch_bounds__(256, 8) void qsim(const float* __restrict__ x,
                                               const float* __restrict__ w,
                                               float* __restrict__ out, int batch) {
  // Batch-shared fused weight matrices W = RZ(w2)*RY(w1)*RZ(w0); SU(2), so
  // only the first ROW (w00, w01) is stored (f32 for accuracy).
  __shared__ float4 wmat[NL * NQ];
  int tid = threadIdx.x;
  if (tid < NL * NQ) {
    const float* wp = &w[tid * 3];
    float t0 = 0.5f * wp[0], t1 = 0.5f * wp[1], t2 = 0.5f * wp[2];
    float c1, s1; sincosf(t1, &s1, &c1);
    float cA, sA; sincosf(t0 + t2, &sA, &cA);
    float cB, sB; sincosf(t0 - t2, &sB, &cB);
    wmat[tid] = make_float4(c1 * cA, -c1 * sA, -s1 * cB, -s1 * sB);
  }
  __syncthreads();

  int lane = tid & 63;
  int b = blockIdx.x * 4 + (tid >> 6);
  if (b >= batch) return;

  float cxv = 1.0f, sxv = 0.0f;
  if (lane < NQ) {
    float th = tanhf(x[b * NQ + lane]) * PI_F;
    sincosf(0.5f * th, &sxv, &cxv);
  }

  // H1: per-lane pre-built fused rows for layers 1..3 (lane i = wire i).
  // Same f32 expressions + RNE pack as the old per-gate build.
  float u00l[NL], u01l[NL];
  {
    int wlane = (lane < NQ) ? lane : 0;
#pragma unroll
    for (int l = 1; l < NL; ++l) {
      float4 wa = wmat[l * NQ + wlane];
      v2 wa0 = {wa.x, wa.y}, wa1 = {wa.z, wa.w};
      v2 u00 = cxv * wa0 + sxv * wa1;
      v2 u01 = cxv * wa1 - sxv * wa0;
      u00l[l] = pack16(u00.x, u00.y);
      u01l[l] = pack16(u01.x, u01.y);
    }
  }

  // Composed lane-permutation for the 5 lane-lane CNOTs.
  int srcl4;
  {
    int t = lane;
    t ^= (t >> 1) & 1;
    t ^= ((t >> 2) & 1) << 1;
    t ^= ((t >> 3) & 1) << 2;
    t ^= ((t >> 4) & 1) << 3;
    t ^= ((t >> 5) & 1) << 4;
    srcl4 = t << 2;
  }

  // Per-lane sign masks for lane bit k: hi-half (im) bit31, lo-half (re) bit15.
  int sgnh[6], sgnl[6];
#pragma unroll
  for (int k = 0; k < 6; ++k) {
    int bit = (lane >> k) & 1;
    sgnh[k] = bit << 31;
    sgnl[k] = bit << 15;
  }

  float s[16];
  // Layer 0 single-qubit part: direct product state (|0> start), then CNOTs.
  // (R0-verbatim path.)
  init_product(s, wmat, cxv, sxv, lane);
  cnot_block(s, lane, srcl4);

  layer_gates<true>(s, u00l[1], u01l[1], sgnh, sgnl);
  cnot_block(s, lane, srcl4);
  layer_gates<true>(s, u00l[2], u01l[2], sgnh, sgnl);
  cnot_block(s, lane, srcl4);
  layer_gates<true>(s, u00l[3], u01l[3], sgnh, sgnl);
  // Layer 3's FULL CNOT chain absorbed into measurement sign masks (Fi).

  // prob in exact f32 via v_dot2_f32_f16.  (R0-verbatim measurement.)
  float prob[16];
#pragma unroll
  for (int r = 0; r < 16; ++r)
    prob[r] = hdot2(s[r], 0.0f);

  float S0 = 0.0f, S8 = 0.0f, SC = 0.0f, SE = 0.0f, SF = 0.0f;
#pragma unroll
  for (int r = 0; r < 16; ++r) {
    float pr = prob[r];
    S0 += pr;
    S8 += (__builtin_popcount(r & 0x8) & 1) ? -pr : pr;
    SC += (__builtin_popcount(r & 0xC) & 1) ? -pr : pr;
    SE += (__builtin_popcount(r & 0xE) & 1) ? -pr : pr;
    SF += (__builtin_popcount(r & 0xF) & 1) ? -pr : pr;
  }

  // Lane suffix parities (Fi rows).
  int l0 = lane & 1, l1 = (lane >> 1) & 1, l2 = (lane >> 2) & 1;
  int l3 = (lane >> 3) & 1, l4 = (lane >> 4) & 1, l5 = (lane >> 5) & 1;
  int p30 = l4 ^ l5;
  int p38 = p30 ^ l3;
  int p3C = p38 ^ l2;
  int p3E = p3C ^ l1;
  int p3F = p3E ^ l0;
  int p1F = p3F ^ l5;

  float part[10];
  part[0] = p3F ? -SF : SF;
  part[1] = p3F ? -SE : SE;
  part[2] = p3F ? -SC : SC;
  part[3] = p3F ? -S8 : S8;
  part[4] = p3F ? -S0 : S0;
  part[5] = p3E ? -S0 : S0;
  part[6] = p3C ? -S0 : S0;
  part[7] = p38 ? -S0 : S0;
  part[8] = p30 ? -S0 : S0;
  part[9] = p1F ? -SF : SF;

#pragma unroll
  for (int p = 0; p < 10; ++p) {
    float a = part[p];
    a += lxor<1>(a);
    a += lxor<2>(a);
    a += lxor<4>(a);
    a += lxor<8>(a);
    a = plsum16(a);
    a = plsum32(a);
    part[p] = a;
  }

  if (lane == 0) {
#pragma unroll
    for (int q = 0; q < NQ; ++q)
      out[b * NQ + q] = part[9 - q];
  }
}

}  // namespace

extern "C" void kernel_launch(void* const* d_in, const int* in_sizes, int n_in,
                              void* d_out, int out_size, void* d_ws, size_t ws_size,
                              hipStream_t stream) {
  const float* x = (const float*)d_in[0];
  const float* w = (const float*)d_in[1];
  float* out = (float*)d_out;
  int batch = in_sizes[0] / NQ;
  int blocks = (batch + 3) / 4;  // 4 waves/block, 1 batch element per wave
  qsim<<<blocks, 256, 0, stream>>>(x, w, out, batch);
}